// Round 1
// baseline (222.844 us; speedup 1.0000x reference)
//
#include <hip/hip_runtime.h>
#include <math.h>

#define NF       2048      // features / FFT size
#define NB2      1024      // NF/2 (butterflies per stage)
#define NC       10        // classes
#define THREADS  256
#define LOGN     11

__device__ __forceinline__ float2 cmul(float2 a, float2 b) {
    return make_float2(a.x*b.x - a.y*b.y, a.x*b.y + a.y*b.x);
}

// Precompute (per launch, re-done every call since d_ws is re-poisoned):
//   tw[j]  = exp(-2*pi*i*j/2048), j in [0,1024)   -- FFT twiddles
//   rot[j] = exp(+i*w1[j]),        j in [0,2048)   -- layer-2 rotation
__global__ void setup_kernel(const float* __restrict__ w,
                             float2* __restrict__ tw,
                             float2* __restrict__ rot) {
    int j = blockIdx.x * blockDim.x + threadIdx.x;   // 0..2047
    if (j < NB2) {
        double th = -(double)j * (M_PI / 1024.0);
        tw[j] = make_float2((float)cos(th), (float)sin(th));
    }
    if (j < NF) {
        double wv = (double)w[NF + j];
        rot[j] = make_float2((float)cos(wv), (float)sin(wv));
    }
}

// Radix-2 Stockham FFT-2048 in LDS. Data starts in *cur, returns pointer to
// the buffer holding the natural-order result. NO normalization (cancels in
// the final im/|z| readout).
__device__ __forceinline__ float2* fft2048(float2* cur, float2* nxt,
                                           const float2* twl, int tid) {
    #pragma unroll
    for (int t = 0; t < LOGN; ++t) {
        const int s = 1 << t;
        __syncthreads();
        #pragma unroll
        for (int i = 0; i < 4; ++i) {
            const int b = tid + i * THREADS;        // butterfly id 0..1023
            const int q = b & (s - 1);
            const int p = b >> t;
            float2 a = cur[b];                       // = q + s*p
            float2 c = cur[b + NB2];                 // = q + s*(p+m)
            float2 wv = twl[b & ~(s - 1)];           // = p << t
            float2 d = make_float2(a.x - c.x, a.y - c.y);
            const int wa = q + (p << (t + 1));       // q + 2*s*p
            nxt[wa]     = make_float2(a.x + c.x, a.y + c.y);
            nxt[wa + s] = cmul(d, wv);
        }
        float2* tmp = cur; cur = nxt; nxt = tmp;
    }
    __syncthreads();
    return cur;
}

__global__ __launch_bounds__(THREADS) void vpc_kernel(
        const float* __restrict__ x, const float* __restrict__ w,
        const float2* __restrict__ twg, const float2* __restrict__ rotg,
        float* __restrict__ out) {
    __shared__ __align__(16) float2 bufA[NF];
    __shared__ __align__(16) float2 bufB[NF];
    __shared__ __align__(16) float2 twl[NB2];
    const int tid = threadIdx.x;
    const int row = blockIdx.x;

    // Stage twiddle table into LDS (reused 22x per row).
    #pragma unroll
    for (int i = 0; i < 4; ++i) {
        int j = tid + i * THREADS;
        if (j < NB2) twl[j] = twg[j];
    }

    // Layer 1: z = exp(i(x + w0)); adjacent-pair butterfly in registers.
    const float2* xr = (const float2*)(x + (size_t)row * NF);
    const float2* w0 = (const float2*)w;
    #pragma unroll
    for (int i = 0; i < 4; ++i) {
        const int p = tid + i * THREADS;             // pair index 0..1023
        float2 xv = xr[p];
        float2 wv = w0[p];
        float s0, c0, s1, c1;
        sincosf(xv.x + wv.x, &s0, &c0);
        sincosf(xv.y + wv.y, &s1, &c1);
        ((float4*)bufA)[p] = make_float4(c0 + c1, s0 + s1, c0 - c1, s0 - s1);
    }

    float2* cur = fft2048(bufA, bufB, twl, tid);   // sync inside covers loads

    // Layer 2: rotate by exp(i*w1), pair butterfly (in place, thread-local).
    float2* nxt = (cur == bufA) ? bufB : bufA;
    #pragma unroll
    for (int i = 0; i < 4; ++i) {
        const int p = tid + i * THREADS;
        float4 v = ((float4*)cur)[p];
        float4 r = ((const float4*)rotg)[p];         // rot[2p], rot[2p+1]
        float2 z0 = cmul(make_float2(v.x, v.y), make_float2(r.x, r.y));
        float2 z1 = cmul(make_float2(v.z, v.w), make_float2(r.z, r.w));
        ((float4*)cur)[p] = make_float4(z0.x + z1.x, z0.y + z1.y,
                                        z0.x - z1.x, z0.y - z1.y);
    }

    cur = fft2048(cur, nxt, twl, tid);             // sync inside covers rotate

    // Readout: logits = 5*im/|z| for bins 0..9, softmax, store.
    if (tid == 0) {
        float lg[NC];
        float mx = -1e30f;
        #pragma unroll
        for (int i = 0; i < NC; ++i) {
            float2 zz = cur[i];
            float mag = sqrtf(zz.x*zz.x + zz.y*zz.y);
            float l = 5.0f * zz.y / fmaxf(mag, 1e-30f);
            lg[i] = l;
            mx = fmaxf(mx, l);
        }
        float sum = 0.f;
        #pragma unroll
        for (int i = 0; i < NC; ++i) { lg[i] = expf(lg[i] - mx); sum += lg[i]; }
        const float inv = 1.0f / sum;
        float* o = out + (size_t)row * NC;
        #pragma unroll
        for (int i = 0; i < NC; ++i) o[i] = lg[i] * inv;
    }
}

extern "C" void kernel_launch(void* const* d_in, const int* in_sizes, int n_in,
                              void* d_out, int out_size, void* d_ws, size_t ws_size,
                              hipStream_t stream) {
    const float* x = (const float*)d_in[0];      // (8192, 2048) f32
    const float* w = (const float*)d_in[1];      // (4096,) f32
    float* out = (float*)d_out;                  // (8192, 10) f32

    // Workspace layout: tw[1024] float2 (8KB) | rot[2048] float2 (16KB)
    float2* tw  = (float2*)d_ws;
    float2* rot = tw + NB2;

    setup_kernel<<<8, THREADS, 0, stream>>>(w, tw, rot);
    vpc_kernel<<<8192, THREADS, 0, stream>>>(x, w, tw, rot, out);
}

// Round 3
// 156.622 us; speedup vs baseline: 1.4228x; 1.4228x over previous
//
#include <hip/hip_runtime.h>
#include <math.h>

#define NF       2048
#define NC       10
#define THREADS  256

// XOR swizzle on float2 index: spreads strided stage-writes across bank slots
// while keeping bit0 (pair adjacency -> float4 ops stay legal) and keeping
// linear reads conflict-free. Bijective within [0,2048).
__device__ __forceinline__ int swz(int i) { return i ^ (((i >> 4) & 7) << 1); }

__device__ __forceinline__ float2 cadd(float2 a, float2 b){ return make_float2(a.x+b.x, a.y+b.y); }
__device__ __forceinline__ float2 csub(float2 a, float2 b){ return make_float2(a.x-b.x, a.y-b.y); }
__device__ __forceinline__ float2 cmul(float2 a, float2 b){
    return make_float2(a.x*b.x - a.y*b.y, a.x*b.y + a.y*b.x);
}
__device__ __forceinline__ float2 mul_mi(float2 d){ return make_float2(d.y, -d.x); }      // d * (-i)
__device__ __forceinline__ float2 mul_w1(float2 d){                                        // d * exp(-i*pi/4)
    const float C = 0.70710678118654752f;
    return make_float2(C*(d.x + d.y), C*(d.y - d.x));
}
__device__ __forceinline__ float2 mul_w3(float2 d){                                        // d * exp(-3i*pi/4)
    const float C = 0.70710678118654752f;
    return make_float2(C*(d.y - d.x), -C*(d.x + d.y));
}

// One radix-8 Stockham stage (cumulative sub-FFT size S in {1,8,64}).
template<int S>
__device__ __forceinline__ void stage8(const float2* cur, float2* nxt,
                                       const float2* twl, int tid)
{
    __syncthreads();
    const int q  = tid & (S - 1);
    const int pb = tid ^ q;                 // S * p
    float2 a0 = cur[swz(tid)];
    float2 a1 = cur[swz(tid + 256)];
    float2 a2 = cur[swz(tid + 512)];
    float2 a3 = cur[swz(tid + 768)];
    float2 a4 = cur[swz(tid + 1024)];
    float2 a5 = cur[swz(tid + 1280)];
    float2 a6 = cur[swz(tid + 1536)];
    float2 a7 = cur[swz(tid + 1792)];
    // DFT-8 (3 radix-2 stages in registers)
    float2 u0 = cadd(a0,a4), u1 = csub(a0,a4);
    float2 u2 = cadd(a1,a5), u3 = mul_w1(csub(a1,a5));
    float2 u4 = cadd(a2,a6), u5 = mul_mi(csub(a2,a6));
    float2 u6 = cadd(a3,a7), u7 = mul_w3(csub(a3,a7));
    float2 v0 = cadd(u0,u4), v2 = csub(u0,u4);
    float2 v1 = cadd(u1,u5), v3 = csub(u1,u5);
    float2 v4 = cadd(u2,u6), v6 = mul_mi(csub(u2,u6));
    float2 v5 = cadd(u3,u7), v7 = mul_mi(csub(u3,u7));
    float2 y0 = cadd(v0,v4), y4 = csub(v0,v4);
    float2 y1 = cadd(v1,v5), y5 = csub(v1,v5);
    float2 y2 = cadd(v2,v6), y6 = csub(v2,v6);
    float2 y3 = cadd(v3,v7), y7 = csub(v3,v7);
    // stage twiddles W^k, W = exp(-2*pi*i*pb/2048); powers by squaring
    float2 w1 = twl[pb];
    float2 w2 = cmul(w1,w1);
    float2 w3 = cmul(w2,w1);
    float2 w4 = cmul(w2,w2);
    float2 w5 = cmul(w4,w1);
    float2 w6 = cmul(w4,w2);
    float2 w7 = cmul(w4,w3);
    y1 = cmul(y1,w1); y2 = cmul(y2,w2); y3 = cmul(y3,w3);
    y4 = cmul(y4,w4); y5 = cmul(y5,w5); y6 = cmul(y6,w6); y7 = cmul(y7,w7);
    const int base = q + 8 * pb;
    nxt[swz(base)]       = y0;
    nxt[swz(base +   S)] = y1;
    nxt[swz(base + 2*S)] = y2;
    nxt[swz(base + 3*S)] = y3;
    nxt[swz(base + 4*S)] = y4;
    nxt[swz(base + 5*S)] = y5;
    nxt[swz(base + 6*S)] = y6;
    nxt[swz(base + 7*S)] = y7;
}

// Final radix-4 stage (S=512), twiddle-free (p=0). Full version (FFT1 only).
__device__ __forceinline__ void stage4_full(const float2* cur, float2* nxt, int tid)
{
    __syncthreads();
    #pragma unroll
    for (int j = 0; j < 2; ++j) {
        const int b = tid + 256*j;
        float2 a0 = cur[swz(b)];
        float2 a1 = cur[swz(b + 512)];
        float2 a2 = cur[swz(b + 1024)];
        float2 a3 = cur[swz(b + 1536)];
        float2 s0 = cadd(a0,a2), s1 = cadd(a1,a3);
        float2 d0 = csub(a0,a2), d1 = mul_mi(csub(a1,a3));
        nxt[swz(b)]        = cadd(s0,s1);
        nxt[swz(b + 512)]  = cadd(d0,d1);
        nxt[swz(b + 1024)] = csub(s0,s1);
        nxt[swz(b + 1536)] = csub(d0,d1);
    }
}

// Fully fused: no workspace, no second kernel, no cross-kernel state.
__global__ __launch_bounds__(THREADS) void vpc_kernel(
        const float* __restrict__ x, const float* __restrict__ w,
        float* __restrict__ out) {
    __shared__ __align__(16) float2 A[NF];
    __shared__ __align__(16) float2 B[NF];
    __shared__ float2 twl[256];
    __shared__ float  smax[NC];
    const int tid = threadIdx.x;
    const int row = blockIdx.x;

    // Twiddle base table built per block: twl[j] = exp(-2*pi*i*j/2048).
    {
        float s, c;
        sincosf(-(float)tid * (float)(M_PI / 1024.0), &s, &c);
        twl[tid] = make_float2(c, s);
    }

    // Layer 1: z = exp(i(x+w0)), adjacent-pair butterfly (scale dropped; all
    // uniform scales cancel in the im/|z| readout).
    const float4* xr4 = (const float4*)(x + (size_t)row * NF);
    const float4* wr4 = (const float4*)w;
    #pragma unroll
    for (int i = 0; i < 2; ++i) {
        const int g = tid + 256*i;           // float4 group = pairs 2g, 2g+1
        float4 xv = xr4[g];
        float4 wv = wr4[g];
        float s0,c0,s1,c1,s2,c2,s3,c3;
        sincosf(xv.x + wv.x, &s0, &c0);
        sincosf(xv.y + wv.y, &s1, &c1);
        sincosf(xv.z + wv.z, &s2, &c2);
        sincosf(xv.w + wv.w, &s3, &c3);
        *(float4*)&A[swz(4*g)]     = make_float4(c0+c1, s0+s1, c0-c1, s0-s1);
        *(float4*)&A[swz(4*g + 2)] = make_float4(c2+c3, s2+s3, c2-c3, s2-s3);
    }

    // FFT1: 2048 = 8*8*8*4   (barrier at top of each stage covers init above)
    stage8<1>(A, B, twl, tid);
    stage8<8>(B, A, twl, tid);
    stage8<64>(A, B, twl, tid);
    stage4_full(B, A, tid);

    // Layer 2: rotate by exp(i*w1) (computed from w directly) + pair butterfly.
    __syncthreads();
    const float2* w1r = (const float2*)(w + NF);
    #pragma unroll
    for (int i = 0; i < 4; ++i) {
        const int p = tid + 256*i;
        float4 v = *(const float4*)&A[swz(2*p)];
        float2 wv = w1r[p];                  // w1[2p], w1[2p+1]
        float s0,c0,s1,c1;
        sincosf(wv.x, &s0, &c0);
        sincosf(wv.y, &s1, &c1);
        float2 z0 = cmul(make_float2(v.x,v.y), make_float2(c0,s0));
        float2 z1 = cmul(make_float2(v.z,v.w), make_float2(c1,s1));
        *(float4*)&A[swz(2*p)] = make_float4(z0.x+z1.x, z0.y+z1.y,
                                             z0.x-z1.x, z0.y-z1.y);
    }

    // FFT2: 3 radix-8 stages; final radix-4 evaluated only for bins 0..9.
    stage8<1>(A, B, twl, tid);
    stage8<8>(B, A, twl, tid);
    stage8<64>(A, B, twl, tid);

    __syncthreads();
    if (tid < NC) {
        float2 a0 = B[swz(tid)];
        float2 a1 = B[swz(tid + 512)];
        float2 a2 = B[swz(tid + 1024)];
        float2 a3 = B[swz(tid + 1536)];
        float2 y = cadd(cadd(a0,a2), cadd(a1,a3));   // bin tid (k=0, twiddle-free)
        float mag = sqrtf(y.x*y.x + y.y*y.y);
        smax[tid] = 5.0f * y.y / fmaxf(mag, 1e-30f);
    }
    __syncthreads();
    if (tid < NC) {
        float l = smax[tid];
        float mx = smax[0];
        #pragma unroll
        for (int j = 1; j < NC; ++j) mx = fmaxf(mx, smax[j]);
        float s = 0.f;
        #pragma unroll
        for (int j = 0; j < NC; ++j) s += __expf(smax[j] - mx);
        out[(size_t)row * NC + tid] = __expf(l - mx) / s;
    }
}

extern "C" void kernel_launch(void* const* d_in, const int* in_sizes, int n_in,
                              void* d_out, int out_size, void* d_ws, size_t ws_size,
                              hipStream_t stream) {
    const float* x = (const float*)d_in[0];   // (8192, 2048) f32
    const float* w = (const float*)d_in[1];   // (4096,) f32
    float* out = (float*)d_out;               // (8192, 10) f32
    (void)d_ws; (void)ws_size;                // intentionally unused

    vpc_kernel<<<8192, THREADS, 0, stream>>>(x, w, out);
}

// Round 4
// 135.759 us; speedup vs baseline: 1.6415x; 1.1537x over previous
//
#include <hip/hip_runtime.h>
#include <math.h>

#define NF       2048
#define NC       10
#define THREADS  256

// XOR swizzle on float2 index: spreads strided stage-writes across bank slots
// while preserving bit0 (adjacent pairs stay adjacent -> float4 ops legal) and
// keeping linear reads conflict-free. Bijective within [0,2048).
__device__ __forceinline__ int swz(int i) { return i ^ (((i >> 4) & 7) << 1); }

__device__ __forceinline__ float2 cadd(float2 a, float2 b){ return make_float2(a.x+b.x, a.y+b.y); }
__device__ __forceinline__ float2 csub(float2 a, float2 b){ return make_float2(a.x-b.x, a.y-b.y); }
__device__ __forceinline__ float2 cmul(float2 a, float2 b){
    return make_float2(a.x*b.x - a.y*b.y, a.x*b.y + a.y*b.x);
}
__device__ __forceinline__ float2 mul_mi(float2 d){ return make_float2(d.y, -d.x); }  // d * (-i)
__device__ __forceinline__ float2 mul_w1(float2 d){                                    // d * exp(-i*pi/4)
    const float C = 0.70710678118654752f;
    return make_float2(C*(d.x + d.y), C*(d.y - d.x));
}
__device__ __forceinline__ float2 mul_w3(float2 d){                                    // d * exp(-3i*pi/4)
    const float C = 0.70710678118654752f;
    return make_float2(C*(d.y - d.x), -C*(d.x + d.y));
}

// In-place radix-8 Stockham stage (cumulative sub-FFT size S in {1,8,64}).
// read-all -> barrier -> write-all makes in-place safe.
template<int S>
__device__ __forceinline__ void stage8_ip(float2* buf, const float2* twl, int tid)
{
    __syncthreads();
    const int q  = tid & (S - 1);
    const int pb = tid ^ q;                 // S * p
    float2 a0 = buf[swz(tid)];
    float2 a1 = buf[swz(tid + 256)];
    float2 a2 = buf[swz(tid + 512)];
    float2 a3 = buf[swz(tid + 768)];
    float2 a4 = buf[swz(tid + 1024)];
    float2 a5 = buf[swz(tid + 1280)];
    float2 a6 = buf[swz(tid + 1536)];
    float2 a7 = buf[swz(tid + 1792)];
    // DFT-8 (3 radix-2 stages in registers)
    float2 u0 = cadd(a0,a4), u1 = csub(a0,a4);
    float2 u2 = cadd(a1,a5), u3 = mul_w1(csub(a1,a5));
    float2 u4 = cadd(a2,a6), u5 = mul_mi(csub(a2,a6));
    float2 u6 = cadd(a3,a7), u7 = mul_w3(csub(a3,a7));
    float2 v0 = cadd(u0,u4), v2 = csub(u0,u4);
    float2 v1 = cadd(u1,u5), v3 = csub(u1,u5);
    float2 v4 = cadd(u2,u6), v6 = mul_mi(csub(u2,u6));
    float2 v5 = cadd(u3,u7), v7 = mul_mi(csub(u3,u7));
    float2 y0 = cadd(v0,v4), y4 = csub(v0,v4);
    float2 y1 = cadd(v1,v5), y5 = csub(v1,v5);
    float2 y2 = cadd(v2,v6), y6 = csub(v2,v6);
    float2 y3 = cadd(v3,v7), y7 = csub(v3,v7);
    // stage twiddles W^k, W = exp(-2*pi*i*pb/2048); powers by squaring
    float2 w1 = twl[pb];
    float2 w2 = cmul(w1,w1);
    float2 w3 = cmul(w2,w1);
    float2 w4 = cmul(w2,w2);
    float2 w5 = cmul(w4,w1);
    float2 w6 = cmul(w4,w2);
    float2 w7 = cmul(w4,w3);
    y1 = cmul(y1,w1); y2 = cmul(y2,w2); y3 = cmul(y3,w3);
    y4 = cmul(y4,w4); y5 = cmul(y5,w5); y6 = cmul(y6,w6); y7 = cmul(y7,w7);
    __syncthreads();                        // all reads done before any write
    const int base = q + 8 * pb;
    buf[swz(base)]       = y0;
    buf[swz(base +   S)] = y1;
    buf[swz(base + 2*S)] = y2;
    buf[swz(base + 3*S)] = y3;
    buf[swz(base + 4*S)] = y4;
    buf[swz(base + 5*S)] = y5;
    buf[swz(base + 6*S)] = y6;
    buf[swz(base + 7*S)] = y7;
}

// FFT1 final radix-4 stage (S=512, p=0 -> twiddle-free) FUSED with the
// layer-2 rotation exp(i*w1) and adjacent-pair butterfly. Each thread owns
// element pairs (2t, 2t+1) at offsets {0,512,1024,1536}: two independent
// radix-4 DFTs (u=even elems, v=odd elems), then per offset k the outputs
// land at positions (2t+512k, 2t+1+512k) = pair p = t+256k -> rotate both,
// write (z0+z1, z0-z1). Per-thread read/write addresses identical -> no mid
// barrier needed.
__device__ __forceinline__ void stage4_rot_ip(float2* buf, const float2* w1r, int tid)
{
    __syncthreads();
    float4 R0 = *(const float4*)&buf[swz(2*tid)];
    float4 R1 = *(const float4*)&buf[swz(2*tid + 512)];
    float4 R2 = *(const float4*)&buf[swz(2*tid + 1024)];
    float4 R3 = *(const float4*)&buf[swz(2*tid + 1536)];
    float2 u0 = make_float2(R0.x,R0.y), v0 = make_float2(R0.z,R0.w);
    float2 u1 = make_float2(R1.x,R1.y), v1 = make_float2(R1.z,R1.w);
    float2 u2 = make_float2(R2.x,R2.y), v2 = make_float2(R2.z,R2.w);
    float2 u3 = make_float2(R3.x,R3.y), v3 = make_float2(R3.z,R3.w);
    float2 us0 = cadd(u0,u2), us1 = cadd(u1,u3);
    float2 ud0 = csub(u0,u2), ud1 = mul_mi(csub(u1,u3));
    float2 vs0 = cadd(v0,v2), vs1 = cadd(v1,v3);
    float2 vd0 = csub(v0,v2), vd1 = mul_mi(csub(v1,v3));
    float2 uy[4] = { cadd(us0,us1), cadd(ud0,ud1), csub(us0,us1), csub(ud0,ud1) };
    float2 vy[4] = { cadd(vs0,vs1), cadd(vd0,vd1), csub(vs0,vs1), csub(vd0,vd1) };
    #pragma unroll
    for (int k = 0; k < 4; ++k) {
        float2 wv = w1r[tid + 256*k];       // w1[2p], w1[2p+1], p = t+256k
        float2 r0 = make_float2(__cosf(wv.x), __sinf(wv.x));
        float2 r1 = make_float2(__cosf(wv.y), __sinf(wv.y));
        float2 z0 = cmul(uy[k], r0);
        float2 z1 = cmul(vy[k], r1);
        *(float4*)&buf[swz(2*tid + 512*k)] =
            make_float4(z0.x+z1.x, z0.y+z1.y, z0.x-z1.x, z0.y-z1.y);
    }
}

// Fully fused single kernel: no workspace, no cross-kernel state.
__global__ __launch_bounds__(THREADS, 8) void vpc_kernel(
        const float* __restrict__ x, const float* __restrict__ w,
        float* __restrict__ out) {
    __shared__ __align__(16) float2 A[NF];
    __shared__ __align__(16) float2 twl[256];
    __shared__ float  smax[NC];
    const int tid = threadIdx.x;
    const int row = blockIdx.x;

    // Twiddle base table: twl[j] = exp(-2*pi*i*j/2048). Native trig: arg
    // magnitude < pi -> well within v_sin/v_cos accurate range.
    {
        float a = -(float)tid * (float)(M_PI / 1024.0);
        twl[tid] = make_float2(__cosf(a), __sinf(a));
    }

    // Layer 1: z = exp(i(x+w0)), adjacent-pair butterfly (uniform scales all
    // cancel in the im/|z| readout, so they are dropped throughout).
    const float4* xr4 = (const float4*)(x + (size_t)row * NF);
    const float4* wr4 = (const float4*)w;
    #pragma unroll
    for (int i = 0; i < 2; ++i) {
        const int g = tid + 256*i;           // float4 group = pairs 2g, 2g+1
        float4 xv = xr4[g];
        float4 wv = wr4[g];
        float a0 = xv.x + wv.x, a1 = xv.y + wv.y;
        float a2 = xv.z + wv.z, a3 = xv.w + wv.w;
        float c0 = __cosf(a0), s0 = __sinf(a0);
        float c1 = __cosf(a1), s1 = __sinf(a1);
        float c2 = __cosf(a2), s2 = __sinf(a2);
        float c3 = __cosf(a3), s3 = __sinf(a3);
        *(float4*)&A[swz(4*g)]     = make_float4(c0+c1, s0+s1, c0-c1, s0-s1);
        *(float4*)&A[swz(4*g + 2)] = make_float4(c2+c3, s2+s3, c2-c3, s2-s3);
    }

    // FFT1: 2048 = 8*8*8*4, last stage fused with layer-2 rotate+butterfly.
    stage8_ip<1> (A, twl, tid);
    stage8_ip<8> (A, twl, tid);
    stage8_ip<64>(A, twl, tid);
    stage4_rot_ip(A, (const float2*)(w + NF), tid);

    // FFT2: 3 radix-8 stages; final radix-4 evaluated only for bins 0..9.
    stage8_ip<1> (A, twl, tid);
    stage8_ip<8> (A, twl, tid);
    stage8_ip<64>(A, twl, tid);

    __syncthreads();
    if (tid < NC) {
        float2 a0 = A[swz(tid)];
        float2 a1 = A[swz(tid + 512)];
        float2 a2 = A[swz(tid + 1024)];
        float2 a3 = A[swz(tid + 1536)];
        float2 y = cadd(cadd(a0,a2), cadd(a1,a3));   // bin tid (k=0, twiddle-free)
        float mag = sqrtf(y.x*y.x + y.y*y.y);
        smax[tid] = 5.0f * y.y / fmaxf(mag, 1e-30f);
    }
    __syncthreads();
    if (tid < NC) {
        float l = smax[tid];
        float mx = smax[0];
        #pragma unroll
        for (int j = 1; j < NC; ++j) mx = fmaxf(mx, smax[j]);
        float s = 0.f;
        #pragma unroll
        for (int j = 0; j < NC; ++j) s += __expf(smax[j] - mx);
        out[(size_t)row * NC + tid] = __expf(l - mx) / s;
    }
}

extern "C" void kernel_launch(void* const* d_in, const int* in_sizes, int n_in,
                              void* d_out, int out_size, void* d_ws, size_t ws_size,
                              hipStream_t stream) {
    const float* x = (const float*)d_in[0];   // (8192, 2048) f32
    const float* w = (const float*)d_in[1];   // (4096,) f32
    float* out = (float*)d_out;               // (8192, 10) f32
    (void)d_ws; (void)ws_size;                // intentionally unused

    vpc_kernel<<<8192, THREADS, 0, stream>>>(x, w, out);
}

// Round 5
// 126.680 us; speedup vs baseline: 1.7591x; 1.0717x over previous
//
#include <hip/hip_runtime.h>
#include <math.h>

#define NF       2048
#define NC       10
#define THREADS  256

// XOR swizzle on float2 index: spreads strided stage-writes across bank slots
// while preserving bit0 (adjacent pairs stay adjacent -> float4 ops legal) and
// keeping linear reads conflict-free. Bijective within [0,2048).
// Key identity (used for all reads): the mask depends only on bits 4-6 of i
// and lands in bits 1-3, so swz(i + 256m) == swz(i) + 256m and
// swz(2t + 512k) == swz(2t) + 512k  -> read addresses fold to base+imm.
__device__ __forceinline__ int swz(int i) { return i ^ (((i >> 4) & 7) << 1); }

__device__ __forceinline__ float2 cadd(float2 a, float2 b){ return make_float2(a.x+b.x, a.y+b.y); }
__device__ __forceinline__ float2 csub(float2 a, float2 b){ return make_float2(a.x-b.x, a.y-b.y); }
__device__ __forceinline__ float2 cmul(float2 a, float2 b){
    return make_float2(a.x*b.x - a.y*b.y, a.x*b.y + a.y*b.x);
}
__device__ __forceinline__ float2 mul_mi(float2 d){ return make_float2(d.y, -d.x); }  // d * (-i)
__device__ __forceinline__ float2 mul_w1(float2 d){                                    // d * exp(-i*pi/4)
    const float C = 0.70710678118654752f;
    return make_float2(C*(d.x + d.y), C*(d.y - d.x));
}
__device__ __forceinline__ float2 mul_w3(float2 d){                                    // d * exp(-3i*pi/4)
    const float C = 0.70710678118654752f;
    return make_float2(C*(d.y - d.x), -C*(d.x + d.y));
}

// In-place radix-8 Stockham stage (cumulative sub-FFT size S in {1,8,64}).
// Entry barrier: previous stage's writes visible. Post-load barrier: ALL
// threads' reads complete before ANY write -> in-place safe, and stores can
// retire during the twiddle-chain compute (shrinks live ranges).
template<int S>
__device__ __forceinline__ void stage8_ip(float2* __restrict__ buf,
                                          const float2* __restrict__ twl,
                                          int tid, int rbase)
{
    __syncthreads();
    float2 a0 = buf[rbase       ];
    float2 a1 = buf[rbase +  256];
    float2 a2 = buf[rbase +  512];
    float2 a3 = buf[rbase +  768];
    float2 a4 = buf[rbase + 1024];
    float2 a5 = buf[rbase + 1280];
    float2 a6 = buf[rbase + 1536];
    float2 a7 = buf[rbase + 1792];
    const int q  = tid & (S - 1);
    const int pb = tid ^ q;                 // S * p
    float2 w1 = twl[pb];                    // read-only table: no hazard
    __syncthreads();                        // all buf reads done chip-wide
    // DFT-8 (3 radix-2 stages in registers)
    float2 u0 = cadd(a0,a4), u1 = csub(a0,a4);
    float2 u2 = cadd(a1,a5), u3 = mul_w1(csub(a1,a5));
    float2 u4 = cadd(a2,a6), u5 = mul_mi(csub(a2,a6));
    float2 u6 = cadd(a3,a7), u7 = mul_w3(csub(a3,a7));
    float2 v0 = cadd(u0,u4), v2 = csub(u0,u4);
    float2 v1 = cadd(u1,u5), v3 = csub(u1,u5);
    float2 v4 = cadd(u2,u6), v6 = mul_mi(csub(u2,u6));
    float2 v5 = cadd(u3,u7), v7 = mul_mi(csub(u3,u7));
    const int base = q + 8 * pb;
    {   // y0 needs no twiddle: store first to free registers early
        float2 y0 = cadd(cadd(u0,u4), cadd(u2,u6));  // v0+v4
        buf[swz(base)] = y0;
    }
    float2 v4b = cadd(u2,u6);
    float2 y4 = csub(v0,v4b);
    float2 w2 = cmul(w1,w1);
    float2 w4 = cmul(w2,w2);
    buf[swz(base + 4*S)] = cmul(y4,w4);
    float2 y1 = cadd(v1,v5), y5 = csub(v1,v5);
    buf[swz(base +   S)] = cmul(y1,w1);
    float2 w5 = cmul(w4,w1);
    buf[swz(base + 5*S)] = cmul(y5,w5);
    float2 y2 = cadd(v2,v6), y6 = csub(v2,v6);
    buf[swz(base + 2*S)] = cmul(y2,w2);
    float2 w6 = cmul(w4,w2);
    buf[swz(base + 6*S)] = cmul(y6,w6);
    float2 y3 = cadd(v3,v7), y7 = csub(v3,v7);
    float2 w3 = cmul(w2,w1);
    buf[swz(base + 3*S)] = cmul(y3,w3);
    float2 w7 = cmul(w4,w3);
    buf[swz(base + 7*S)] = cmul(y7,w7);
}

// FFT1 final radix-4 stage (S=512, p=0 -> twiddle-free) FUSED with layer-2
// rotation exp(i*w1) + adjacent-pair butterfly. Each thread reads and writes
// the SAME addresses (bijective ownership) -> single entry barrier suffices.
__device__ __forceinline__ void stage4_rot_ip(float2* __restrict__ buf,
                                              const float2* __restrict__ w1r,
                                              int tid, int r2base)
{
    __syncthreads();
    float4 R0 = *(const float4*)&buf[r2base       ];
    float4 R1 = *(const float4*)&buf[r2base +  512];
    float4 R2 = *(const float4*)&buf[r2base + 1024];
    float4 R3 = *(const float4*)&buf[r2base + 1536];
    float2 u0 = make_float2(R0.x,R0.y), v0 = make_float2(R0.z,R0.w);
    float2 u1 = make_float2(R1.x,R1.y), v1 = make_float2(R1.z,R1.w);
    float2 u2 = make_float2(R2.x,R2.y), v2 = make_float2(R2.z,R2.w);
    float2 u3 = make_float2(R3.x,R3.y), v3 = make_float2(R3.z,R3.w);
    float2 us0 = cadd(u0,u2), us1 = cadd(u1,u3);
    float2 ud0 = csub(u0,u2), ud1 = mul_mi(csub(u1,u3));
    float2 vs0 = cadd(v0,v2), vs1 = cadd(v1,v3);
    float2 vd0 = csub(v0,v2), vd1 = mul_mi(csub(v1,v3));
    float2 uy[4] = { cadd(us0,us1), cadd(ud0,ud1), csub(us0,us1), csub(ud0,ud1) };
    float2 vy[4] = { cadd(vs0,vs1), cadd(vd0,vd1), csub(vs0,vs1), csub(vd0,vd1) };
    #pragma unroll
    for (int k = 0; k < 4; ++k) {
        float2 wv = w1r[tid + 256*k];       // w1[2p], w1[2p+1], p = t+256k
        float s0, c0, s1, c1;
        __sincosf(wv.x, &s0, &c0);
        __sincosf(wv.y, &s1, &c1);
        float2 z0 = cmul(uy[k], make_float2(c0,s0));
        float2 z1 = cmul(vy[k], make_float2(c1,s1));
        *(float4*)&buf[r2base + 512*k] =
            make_float4(z0.x+z1.x, z0.y+z1.y, z0.x-z1.x, z0.y-z1.y);
    }
}

// Fully fused single kernel: no workspace, no cross-kernel state.
__global__ __launch_bounds__(THREADS, 6) void vpc_kernel(
        const float* __restrict__ x, const float* __restrict__ w,
        float* __restrict__ out) {
    __shared__ __align__(16) float2 A[NF];
    __shared__ __align__(16) float2 twl[256];
    __shared__ float  smax[NC];
    const int tid   = threadIdx.x;
    const int row   = blockIdx.x;
    const int rbase  = swz(tid);
    const int r2base = swz(2*tid);

    // Twiddle base table: twl[j] = exp(-2*pi*i*j/2048).
    {
        float a = -(float)tid * (float)(M_PI / 1024.0);
        float s, c;
        __sincosf(a, &s, &c);
        twl[tid] = make_float2(c, s);
    }

    // Layer 1: z = exp(i(x+w0)), adjacent-pair butterfly (uniform scales all
    // cancel in the im/|z| readout, so they are dropped throughout).
    const float4* xr4 = (const float4*)(x + (size_t)row * NF);
    const float4* wr4 = (const float4*)w;
    #pragma unroll
    for (int i = 0; i < 2; ++i) {
        const int g = tid + 256*i;           // float4 group = pairs 2g, 2g+1
        float4 xv = xr4[g];
        float4 wv = wr4[g];
        float s0,c0,s1,c1,s2,c2,s3,c3;
        __sincosf(xv.x + wv.x, &s0, &c0);
        __sincosf(xv.y + wv.y, &s1, &c1);
        __sincosf(xv.z + wv.z, &s2, &c2);
        __sincosf(xv.w + wv.w, &s3, &c3);
        *(float4*)&A[swz(4*g)]     = make_float4(c0+c1, s0+s1, c0-c1, s0-s1);
        *(float4*)&A[swz(4*g + 2)] = make_float4(c2+c3, s2+s3, c2-c3, s2-s3);
    }

    // FFT1: 2048 = 8*8*8*4, last stage fused with layer-2 rotate+butterfly.
    stage8_ip<1> (A, twl, tid, rbase);
    stage8_ip<8> (A, twl, tid, rbase);
    stage8_ip<64>(A, twl, tid, rbase);
    stage4_rot_ip(A, (const float2*)(w + NF), tid, r2base);

    // FFT2: 3 radix-8 stages; final radix-4 evaluated only for bins 0..9.
    stage8_ip<1> (A, twl, tid, rbase);
    stage8_ip<8> (A, twl, tid, rbase);
    stage8_ip<64>(A, twl, tid, rbase);

    __syncthreads();
    if (tid < NC) {
        // swz(tid)=tid and swz(tid+512m)=tid+512m for tid<16 (mask bits = 0).
        float2 a0 = A[tid];
        float2 a1 = A[tid + 512];
        float2 a2 = A[tid + 1024];
        float2 a3 = A[tid + 1536];
        float2 y = cadd(cadd(a0,a2), cadd(a1,a3));   // bin tid (k=0, twiddle-free)
        float mag = sqrtf(y.x*y.x + y.y*y.y);
        smax[tid] = 5.0f * y.y / fmaxf(mag, 1e-30f);
    }
    __syncthreads();
    if (tid < NC) {
        float l = smax[tid];
        float mx = smax[0];
        #pragma unroll
        for (int j = 1; j < NC; ++j) mx = fmaxf(mx, smax[j]);
        float s = 0.f;
        #pragma unroll
        for (int j = 0; j < NC; ++j) s += __expf(smax[j] - mx);
        out[(size_t)row * NC + tid] = __expf(l - mx) / s;
    }
}

extern "C" void kernel_launch(void* const* d_in, const int* in_sizes, int n_in,
                              void* d_out, int out_size, void* d_ws, size_t ws_size,
                              hipStream_t stream) {
    const float* x = (const float*)d_in[0];   // (8192, 2048) f32
    const float* w = (const float*)d_in[1];   // (4096,) f32
    float* out = (float*)d_out;               // (8192, 10) f32
    (void)d_ws; (void)ws_size;                // intentionally unused

    vpc_kernel<<<8192, THREADS, 0, stream>>>(x, w, out);
}

// Round 6
// 125.202 us; speedup vs baseline: 1.7799x; 1.0118x over previous
//
#include <hip/hip_runtime.h>
#include <math.h>

#define NF       2048
#define NC       10
#define THREADS  256

// XOR swizzle on float2 index: spreads strided stage-writes across bank slots
// while preserving bit0 (adjacent pairs stay adjacent -> float4 ops legal) and
// keeping linear reads conflict-free. Bijective within [0,2048).
// Identity used everywhere: mask depends only on bits 4-6 of i and lands in
// bits 1-3, so swz(i + 256m) == swz(i) + 256m, swz(2t+512k) == swz(2t)+512k,
// and for q<16: swz(q + 64r) == (q + 64r) ^ ((r&1)<<3).
__device__ __forceinline__ int swz(int i) { return i ^ (((i >> 4) & 7) << 1); }

__device__ __forceinline__ float2 cadd(float2 a, float2 b){ return make_float2(a.x+b.x, a.y+b.y); }
__device__ __forceinline__ float2 csub(float2 a, float2 b){ return make_float2(a.x-b.x, a.y-b.y); }
__device__ __forceinline__ float2 cmul(float2 a, float2 b){
    return make_float2(a.x*b.x - a.y*b.y, a.x*b.y + a.y*b.x);
}
__device__ __forceinline__ float2 mul_mi(float2 d){ return make_float2(d.y, -d.x); }  // d * (-i)
__device__ __forceinline__ float2 mul_w1(float2 d){                                    // d * exp(-i*pi/4)
    const float C = 0.70710678118654752f;
    return make_float2(C*(d.x + d.y), C*(d.y - d.x));
}
__device__ __forceinline__ float2 mul_w3(float2 d){                                    // d * exp(-3i*pi/4)
    const float C = 0.70710678118654752f;
    return make_float2(C*(d.y - d.x), -C*(d.x + d.y));
}

// In-place radix-8 Stockham stage (cumulative sub-FFT size S in {1,8,64}).
// Entry barrier: previous stage's writes visible. Post-load barrier: ALL
// threads' reads complete before ANY write -> in-place safe.
template<int S>
__device__ __forceinline__ void stage8_ip(float2* __restrict__ buf,
                                          const float2* __restrict__ twl,
                                          int tid, int rbase)
{
    __syncthreads();
    float2 a0 = buf[rbase       ];
    float2 a1 = buf[rbase +  256];
    float2 a2 = buf[rbase +  512];
    float2 a3 = buf[rbase +  768];
    float2 a4 = buf[rbase + 1024];
    float2 a5 = buf[rbase + 1280];
    float2 a6 = buf[rbase + 1536];
    float2 a7 = buf[rbase + 1792];
    const int q  = tid & (S - 1);
    const int pb = tid ^ q;                 // S * p
    float2 w1 = twl[pb];                    // read-only table: no hazard
    __syncthreads();                        // all buf reads done block-wide
    // DFT-8 (3 radix-2 stages in registers)
    float2 u0 = cadd(a0,a4), u1 = csub(a0,a4);
    float2 u2 = cadd(a1,a5), u3 = mul_w1(csub(a1,a5));
    float2 u4 = cadd(a2,a6), u5 = mul_mi(csub(a2,a6));
    float2 u6 = cadd(a3,a7), u7 = mul_w3(csub(a3,a7));
    float2 v0 = cadd(u0,u4), v2 = csub(u0,u4);
    float2 v1 = cadd(u1,u5), v3 = csub(u1,u5);
    float2 v4 = cadd(u2,u6), v6 = mul_mi(csub(u2,u6));
    float2 v5 = cadd(u3,u7), v7 = mul_mi(csub(u3,u7));
    const int base = q + 8 * pb;
    buf[swz(base)] = cadd(v0,v4);           // y0: no twiddle, store first
    float2 y4 = csub(v0,v4);
    float2 w2 = cmul(w1,w1);
    float2 w4 = cmul(w2,w2);
    buf[swz(base + 4*S)] = cmul(y4,w4);
    float2 y1 = cadd(v1,v5), y5 = csub(v1,v5);
    buf[swz(base +   S)] = cmul(y1,w1);
    float2 w5 = cmul(w4,w1);
    buf[swz(base + 5*S)] = cmul(y5,w5);
    float2 y2 = cadd(v2,v6), y6 = csub(v2,v6);
    buf[swz(base + 2*S)] = cmul(y2,w2);
    float2 w6 = cmul(w4,w2);
    buf[swz(base + 6*S)] = cmul(y6,w6);
    float2 y3 = cadd(v3,v7), y7 = csub(v3,v7);
    float2 w3 = cmul(w2,w1);
    buf[swz(base + 3*S)] = cmul(y3,w3);
    float2 w7 = cmul(w4,w3);
    buf[swz(base + 7*S)] = cmul(y7,w7);
}

// Truncated S=8 stage for FFT2: downstream only reads positions with
// residue mod 64 in [0,10) = y0 (residues 0..7, every thread) and y1
// (residues 8..9, threads with q<2). Each thread's y0/y1 depend only on its
// own 8 reads of fully-valid data, so the unwritten positions (stale) are
// never read downstream.
__device__ __forceinline__ void stage8_trunc(float2* __restrict__ buf,
                                             const float2* __restrict__ twl,
                                             int tid, int rbase)
{
    __syncthreads();
    float2 a0 = buf[rbase       ];
    float2 a1 = buf[rbase +  256];
    float2 a2 = buf[rbase +  512];
    float2 a3 = buf[rbase +  768];
    float2 a4 = buf[rbase + 1024];
    float2 a5 = buf[rbase + 1280];
    float2 a6 = buf[rbase + 1536];
    float2 a7 = buf[rbase + 1792];
    const int q  = tid & 7;
    const int pb = tid ^ q;                 // 8 * p
    float2 w1 = twl[pb];
    __syncthreads();
    const int base = q + 8 * pb;
    float2 y0 = cadd(cadd(cadd(a0,a4), cadd(a2,a6)),
                     cadd(cadd(a1,a5), cadd(a3,a7)));
    buf[swz(base)] = y0;
    if (q < 2) {
        float2 u1 = csub(a0,a4);
        float2 u3 = mul_w1(csub(a1,a5));
        float2 u5 = mul_mi(csub(a2,a6));
        float2 u7 = mul_w3(csub(a3,a7));
        float2 y1 = cadd(cadd(u1,u5), cadd(u3,u7));
        buf[swz(base + 8)] = cmul(y1, w1);
    }
}

// FFT1 final radix-4 stage (S=512, p=0 -> twiddle-free) FUSED with layer-2
// rotation exp(i*w1) + adjacent-pair butterfly. Each thread reads and writes
// the SAME addresses (bijective ownership) -> single entry barrier suffices.
__device__ __forceinline__ void stage4_rot_ip(float2* __restrict__ buf,
                                              const float2* __restrict__ w1r,
                                              int tid, int r2base)
{
    __syncthreads();
    float4 R0 = *(const float4*)&buf[r2base       ];
    float4 R1 = *(const float4*)&buf[r2base +  512];
    float4 R2 = *(const float4*)&buf[r2base + 1024];
    float4 R3 = *(const float4*)&buf[r2base + 1536];
    float2 u0 = make_float2(R0.x,R0.y), v0 = make_float2(R0.z,R0.w);
    float2 u1 = make_float2(R1.x,R1.y), v1 = make_float2(R1.z,R1.w);
    float2 u2 = make_float2(R2.x,R2.y), v2 = make_float2(R2.z,R2.w);
    float2 u3 = make_float2(R3.x,R3.y), v3 = make_float2(R3.z,R3.w);
    float2 us0 = cadd(u0,u2), us1 = cadd(u1,u3);
    float2 ud0 = csub(u0,u2), ud1 = mul_mi(csub(u1,u3));
    float2 vs0 = cadd(v0,v2), vs1 = cadd(v1,v3);
    float2 vd0 = csub(v0,v2), vd1 = mul_mi(csub(v1,v3));
    float2 uy[4] = { cadd(us0,us1), cadd(ud0,ud1), csub(us0,us1), csub(ud0,ud1) };
    float2 vy[4] = { cadd(vs0,vs1), cadd(vd0,vd1), csub(vs0,vs1), csub(vd0,vd1) };
    #pragma unroll
    for (int k = 0; k < 4; ++k) {
        float2 wv = w1r[tid + 256*k];       // w1[2p], w1[2p+1], p = t+256k
        float s0, c0, s1, c1;
        __sincosf(wv.x, &s0, &c0);
        __sincosf(wv.y, &s1, &c1);
        float2 z0 = cmul(uy[k], make_float2(c0,s0));
        float2 z1 = cmul(vy[k], make_float2(c1,s1));
        *(float4*)&buf[r2base + 512*k] =
            make_float4(z0.x+z1.x, z0.y+z1.y, z0.x-z1.x, z0.y-z1.y);
    }
}

// Fully fused single kernel: no workspace, no cross-kernel state.
__global__ __launch_bounds__(THREADS, 8) void vpc_kernel(
        const float* __restrict__ x, const float* __restrict__ w,
        float* __restrict__ out) {
    __shared__ __align__(16) float2 A[NF];
    __shared__ __align__(16) float2 twl[256];
    __shared__ float  smax[NC];
    const int tid   = threadIdx.x;
    const int row   = blockIdx.x;
    const int rbase  = swz(tid);
    const int r2base = swz(2*tid);

    // Twiddle base table: twl[j] = exp(-2*pi*i*j/2048).
    {
        float a = -(float)tid * (float)(M_PI / 1024.0);
        float s, c;
        __sincosf(a, &s, &c);
        twl[tid] = make_float2(c, s);
    }

    // Layer 1: z = exp(i(x+w0)), adjacent-pair butterfly (uniform scales all
    // cancel in the im/|z| readout, so they are dropped throughout).
    const float4* xr4 = (const float4*)(x + (size_t)row * NF);
    const float4* wr4 = (const float4*)w;
    #pragma unroll
    for (int i = 0; i < 2; ++i) {
        const int g = tid + 256*i;           // float4 group = pairs 2g, 2g+1
        float4 xv = xr4[g];
        float4 wv = wr4[g];
        float s0,c0,s1,c1,s2,c2,s3,c3;
        __sincosf(xv.x + wv.x, &s0, &c0);
        __sincosf(xv.y + wv.y, &s1, &c1);
        __sincosf(xv.z + wv.z, &s2, &c2);
        __sincosf(xv.w + wv.w, &s3, &c3);
        *(float4*)&A[swz(4*g)]     = make_float4(c0+c1, s0+s1, c0-c1, s0-s1);
        *(float4*)&A[swz(4*g + 2)] = make_float4(c2+c3, s2+s3, c2-c3, s2-s3);
    }

    // FFT1: 2048 = 8*8*8*4, last stage fused with layer-2 rotate+butterfly.
    stage8_ip<1> (A, twl, tid, rbase);
    stage8_ip<8> (A, twl, tid, rbase);
    stage8_ip<64>(A, twl, tid, rbase);
    stage4_rot_ip(A, (const float2*)(w + NF), tid, r2base);

    // FFT2, pruned to the 10 needed output bins:
    //   full S=1 stage; truncated S=8 stage (y0 + y1 only);
    //   then bins q<10: X[q] = sum over r<32 of A[swz(q+64r)]
    //   (the S=64 stage's y0 and the final radix-4 k=0 are both plain sums).
    stage8_ip<1>(A, twl, tid, rbase);
    stage8_trunc(A, twl, tid, rbase);

    __syncthreads();
    if (tid < NC) {
        float2 acc = make_float2(0.f, 0.f);
        #pragma unroll 8
        for (int r = 0; r < 32; ++r) {
            int addr = (tid + 64*r) ^ ((r & 1) << 3);   // = swz(tid+64r), tid<16
            acc = cadd(acc, A[addr]);
        }
        float mag = sqrtf(acc.x*acc.x + acc.y*acc.y);
        smax[tid] = 5.0f * acc.y / fmaxf(mag, 1e-30f);
    }
    __syncthreads();
    if (tid < NC) {
        float l = smax[tid];
        float mx = smax[0];
        #pragma unroll
        for (int j = 1; j < NC; ++j) mx = fmaxf(mx, smax[j]);
        float s = 0.f;
        #pragma unroll
        for (int j = 0; j < NC; ++j) s += __expf(smax[j] - mx);
        out[(size_t)row * NC + tid] = __expf(l - mx) / s;
    }
}

extern "C" void kernel_launch(void* const* d_in, const int* in_sizes, int n_in,
                              void* d_out, int out_size, void* d_ws, size_t ws_size,
                              hipStream_t stream) {
    const float* x = (const float*)d_in[0];   // (8192, 2048) f32
    const float* w = (const float*)d_in[1];   // (4096,) f32
    float* out = (float*)d_out;               // (8192, 10) f32
    (void)d_ws; (void)ws_size;                // intentionally unused

    vpc_kernel<<<8192, THREADS, 0, stream>>>(x, w, out);
}

// Round 7
// 118.002 us; speedup vs baseline: 1.8885x; 1.0610x over previous
//
#include <hip/hip_runtime.h>
#include <math.h>

#define NF       2048
#define NC       10
#define THREADS  256

// ext_vector floats -> LLVM emits packed fp32 VOP3P (v_pk_add_f32 /
// v_pk_mul_f32 / v_pk_fma_f32) on gfx950: 2 f32 lanes per instruction.
// HIP's float2 struct does NOT get this lowering.
typedef float f2 __attribute__((ext_vector_type(2)));
typedef float f4 __attribute__((ext_vector_type(4)));

__device__ __forceinline__ f2 mk2(float a, float b){ f2 r; r.x=a; r.y=b; return r; }

// XOR swizzle on f2 index: spreads strided stage-writes across bank slots
// while preserving bit0 (adjacent pairs stay adjacent -> f4 ops legal) and
// keeping linear reads conflict-free. Bijective within [0,2048).
// Identity: mask depends only on bits 4-6 of i and lands in bits 1-3, so
// swz(i+256m)==swz(i)+256m, swz(2t+512k)==swz(2t)+512k, and for q<16:
// swz(q+64r) == (q+64r) ^ ((r&1)<<3).
__device__ __forceinline__ int swz(int i) { return i ^ (((i >> 4) & 7) << 1); }

// complex mul: (ax*bx - ay*by, ax*by + ay*bx) = a.xx*b + a.yy*(-b.y, b.x)
// -> v_pk_mul + v_pk_fma (+swizzle folded into op_sel/neg where possible)
__device__ __forceinline__ f2 cmul(f2 a, f2 b){
    f2 t = mk2(a.x, a.x) * b;
    return mk2(a.y, a.y) * mk2(-b.y, b.x) + t;
}
__device__ __forceinline__ f2 mul_mi(f2 d){ return mk2(d.y, -d.x); }   // d * (-i)
__device__ __forceinline__ f2 mul_w1(f2 d){                             // d * exp(-i*pi/4)
    const float C = 0.70710678118654752f;
    return (d + mk2(d.y, -d.x)) * mk2(C, C);
}
__device__ __forceinline__ f2 mul_w3(f2 d){                             // d * exp(-3i*pi/4)
    const float C = 0.70710678118654752f;
    return (mk2(d.y, -d.y) - mk2(d.x, d.x)) * mk2(C, C);
}

// In-place radix-8 Stockham stage (cumulative sub-FFT size S in {1,8,64}).
// Entry barrier: previous stage's writes visible. Post-load barrier: ALL
// threads' reads complete before ANY write -> in-place safe.
template<int S>
__device__ __forceinline__ void stage8_ip(f2* __restrict__ buf,
                                          const f2* __restrict__ twl,
                                          int tid, int rbase)
{
    __syncthreads();
    f2 a0 = buf[rbase       ];
    f2 a1 = buf[rbase +  256];
    f2 a2 = buf[rbase +  512];
    f2 a3 = buf[rbase +  768];
    f2 a4 = buf[rbase + 1024];
    f2 a5 = buf[rbase + 1280];
    f2 a6 = buf[rbase + 1536];
    f2 a7 = buf[rbase + 1792];
    const int q  = tid & (S - 1);
    const int pb = tid ^ q;                 // S * p
    f2 w1 = twl[pb];                        // read-only table: no hazard
    __syncthreads();                        // all buf reads done block-wide
    // DFT-8 (3 radix-2 stages in registers), packed adds
    f2 u0 = a0+a4, u1 = a0-a4;
    f2 u2 = a1+a5, u3 = mul_w1(a1-a5);
    f2 u4 = a2+a6, u5 = mul_mi(a2-a6);
    f2 u6 = a3+a7, u7 = mul_w3(a3-a7);
    f2 v0 = u0+u4, v2 = u0-u4;
    f2 v1 = u1+u5, v3 = u1-u5;
    f2 v4 = u2+u6, v6 = mul_mi(u2-u6);
    f2 v5 = u3+u7, v7 = mul_mi(u3-u7);
    const int base = q + 8 * pb;
    buf[swz(base)] = v0+v4;                 // y0: no twiddle, store first
    f2 y4 = v0-v4;
    f2 w2 = cmul(w1,w1);
    f2 w4 = cmul(w2,w2);
    buf[swz(base + 4*S)] = cmul(y4,w4);
    f2 y1 = v1+v5, y5 = v1-v5;
    buf[swz(base +   S)] = cmul(y1,w1);
    f2 w5 = cmul(w4,w1);
    buf[swz(base + 5*S)] = cmul(y5,w5);
    f2 y2 = v2+v6, y6 = v2-v6;
    buf[swz(base + 2*S)] = cmul(y2,w2);
    f2 w6 = cmul(w4,w2);
    buf[swz(base + 6*S)] = cmul(y6,w6);
    f2 y3 = v3+v7, y7 = v3-v7;
    f2 w3 = cmul(w2,w1);
    buf[swz(base + 3*S)] = cmul(y3,w3);
    f2 w7 = cmul(w4,w3);
    buf[swz(base + 7*S)] = cmul(y7,w7);
}

// Truncated S=8 stage for FFT2: downstream only reads positions with residue
// mod 64 in [0,10) = y0 (all threads) and y1 (threads with q<2). Each
// thread's y0/y1 depend only on its own 8 fully-valid reads, so stale
// unwritten positions are never read downstream.
__device__ __forceinline__ void stage8_trunc(f2* __restrict__ buf,
                                             const f2* __restrict__ twl,
                                             int tid, int rbase)
{
    __syncthreads();
    f2 a0 = buf[rbase       ];
    f2 a1 = buf[rbase +  256];
    f2 a2 = buf[rbase +  512];
    f2 a3 = buf[rbase +  768];
    f2 a4 = buf[rbase + 1024];
    f2 a5 = buf[rbase + 1280];
    f2 a6 = buf[rbase + 1536];
    f2 a7 = buf[rbase + 1792];
    const int q  = tid & 7;
    const int pb = tid ^ q;                 // 8 * p
    f2 w1 = twl[pb];
    __syncthreads();
    const int base = q + 8 * pb;
    buf[swz(base)] = ((a0+a4) + (a2+a6)) + ((a1+a5) + (a3+a7));
    if (q < 2) {
        f2 u1 = a0-a4;
        f2 u3 = mul_w1(a1-a5);
        f2 u5 = mul_mi(a2-a6);
        f2 u7 = mul_w3(a3-a7);
        buf[swz(base + 8)] = cmul((u1+u5) + (u3+u7), w1);
    }
}

// FFT1 final radix-4 stage (S=512, p=0 -> twiddle-free) FUSED with layer-2
// rotation exp(i*w1) + adjacent-pair butterfly. Each thread reads and writes
// the SAME addresses (bijective ownership) -> single entry barrier suffices.
__device__ __forceinline__ void stage4_rot_ip(f2* __restrict__ buf,
                                              const f2* __restrict__ w1r,
                                              int tid, int r2base)
{
    __syncthreads();
    f4 R0 = *(const f4*)&buf[r2base       ];
    f4 R1 = *(const f4*)&buf[r2base +  512];
    f4 R2 = *(const f4*)&buf[r2base + 1024];
    f4 R3 = *(const f4*)&buf[r2base + 1536];
    f2 u0 = R0.lo, v0 = R0.hi;
    f2 u1 = R1.lo, v1 = R1.hi;
    f2 u2 = R2.lo, v2 = R2.hi;
    f2 u3 = R3.lo, v3 = R3.hi;
    f2 us0 = u0+u2, us1 = u1+u3;
    f2 ud0 = u0-u2, ud1 = mul_mi(u1-u3);
    f2 vs0 = v0+v2, vs1 = v1+v3;
    f2 vd0 = v0-v2, vd1 = mul_mi(v1-v3);
    f2 uy[4] = { us0+us1, ud0+ud1, us0-us1, ud0-ud1 };
    f2 vy[4] = { vs0+vs1, vd0+vd1, vs0-vs1, vd0-vd1 };
    #pragma unroll
    for (int k = 0; k < 4; ++k) {
        f2 wv = w1r[tid + 256*k];           // w1[2p], w1[2p+1], p = t+256k
        float s0, c0, s1, c1;
        __sincosf(wv.x, &s0, &c0);
        __sincosf(wv.y, &s1, &c1);
        f2 z0 = cmul(uy[k], mk2(c0,s0));
        f2 z1 = cmul(vy[k], mk2(c1,s1));
        f4 o; o.lo = z0+z1; o.hi = z0-z1;
        *(f4*)&buf[r2base + 512*k] = o;
    }
}

// Fully fused single kernel: no workspace, no cross-kernel state.
__global__ __launch_bounds__(THREADS, 8) void vpc_kernel(
        const float* __restrict__ x, const float* __restrict__ w,
        float* __restrict__ out) {
    __shared__ __align__(16) f2 A[NF];
    __shared__ __align__(16) f2 twl[256];
    __shared__ float smax[NC];
    const int tid    = threadIdx.x;
    const int row    = blockIdx.x;
    const int rbase  = swz(tid);
    const int r2base = swz(2*tid);

    // Twiddle base table: twl[j] = exp(-2*pi*i*j/2048).
    {
        float a = -(float)tid * (float)(M_PI / 1024.0);
        float s, c;
        __sincosf(a, &s, &c);
        twl[tid] = mk2(c, s);
    }

    // Layer 1: z = exp(i(x+w0)), adjacent-pair butterfly (uniform scales all
    // cancel in the im/|z| readout, so they are dropped throughout).
    const f4* xr4 = (const f4*)(x + (size_t)row * NF);
    const f4* wr4 = (const f4*)w;
    #pragma unroll
    for (int i = 0; i < 2; ++i) {
        const int g = tid + 256*i;           // f4 group = pairs 2g, 2g+1
        f4 xv = xr4[g];
        f4 wv = wr4[g];
        float s0,c0,s1,c1,s2,c2,s3,c3;
        __sincosf(xv.x + wv.x, &s0, &c0);
        __sincosf(xv.y + wv.y, &s1, &c1);
        __sincosf(xv.z + wv.z, &s2, &c2);
        __sincosf(xv.w + wv.w, &s3, &c3);
        f2 z0 = mk2(c0,s0), z1 = mk2(c1,s1);
        f2 z2 = mk2(c2,s2), z3 = mk2(c3,s3);
        f4 o0; o0.lo = z0+z1; o0.hi = z0-z1;
        f4 o1; o1.lo = z2+z3; o1.hi = z2-z3;
        *(f4*)&A[swz(4*g)]     = o0;
        *(f4*)&A[swz(4*g + 2)] = o1;
    }

    // FFT1: 2048 = 8*8*8*4, last stage fused with layer-2 rotate+butterfly.
    stage8_ip<1> (A, twl, tid, rbase);
    stage8_ip<8> (A, twl, tid, rbase);
    stage8_ip<64>(A, twl, tid, rbase);
    stage4_rot_ip(A, (const f2*)(w + NF), tid, r2base);

    // FFT2, pruned to the 10 needed output bins:
    //   full S=1 stage; truncated S=8 stage (y0 + y1 only);
    //   then bins q<10: X[q] = sum over r<32 of A[swz(q+64r)].
    stage8_ip<1>(A, twl, tid, rbase);
    stage8_trunc(A, twl, tid, rbase);

    __syncthreads();
    if (tid < NC) {
        f2 acc = mk2(0.f, 0.f);
        #pragma unroll 8
        for (int r = 0; r < 32; ++r) {
            int addr = (tid + 64*r) ^ ((r & 1) << 3);   // = swz(tid+64r), tid<16
            acc = acc + A[addr];
        }
        float mag = sqrtf(acc.x*acc.x + acc.y*acc.y);
        smax[tid] = 5.0f * acc.y / fmaxf(mag, 1e-30f);
    }
    __syncthreads();
    if (tid < NC) {
        float l = smax[tid];
        float mx = smax[0];
        #pragma unroll
        for (int j = 1; j < NC; ++j) mx = fmaxf(mx, smax[j]);
        float s = 0.f;
        #pragma unroll
        for (int j = 0; j < NC; ++j) s += __expf(smax[j] - mx);
        out[(size_t)row * NC + tid] = __expf(l - mx) / s;
    }
}

extern "C" void kernel_launch(void* const* d_in, const int* in_sizes, int n_in,
                              void* d_out, int out_size, void* d_ws, size_t ws_size,
                              hipStream_t stream) {
    const float* x = (const float*)d_in[0];   // (8192, 2048) f32
    const float* w = (const float*)d_in[1];   // (4096,) f32
    float* out = (float*)d_out;               // (8192, 10) f32
    (void)d_ws; (void)ws_size;                // intentionally unused

    vpc_kernel<<<8192, THREADS, 0, stream>>>(x, w, out);
}